// Round 15
// baseline (1757.484 us; speedup 1.0000x reference)
//
#include <hip/hip_runtime.h>

#define TOK 4096
#define DMODEL 768
#define NSEQ 1024
#define NHEADS 12
#define HD 64
#define DFFN 3072
#define NLAYER 8
#define QKVD 2304

// per-layer W^T element offsets in the all-layers region
#define WT_QKV  0
#define WT_WOUT 1769472
#define WT_W1   2359296
#define WT_W2   4718592
#define WT_LAYER 7077888   // elements per layer (14,155,776 B)

typedef __bf16 bf16_t;
typedef __bf16 bf16x8 __attribute__((ext_vector_type(8)));
typedef float f32x4 __attribute__((ext_vector_type(4)));

__device__ __forceinline__ f32x4 zero4() { f32x4 z = {0.f, 0.f, 0.f, 0.f}; return z; }

__device__ __forceinline__ void gload_lds16(const void* g, void* l) {
  __builtin_amdgcn_global_load_lds((__attribute__((address_space(1))) void*)(g),
                                   (__attribute__((address_space(3))) void*)(l),
                                   16, 0, 0);
}

// XCD-aware bijective chunked remap (m204), x-major output ordering.
__device__ __forceinline__ void swz_block(int gx, int gy, int& bx, int& by) {
  int nwg = gx * gy;
  int orig = blockIdx.y * gx + blockIdx.x;
  int q = nwg >> 3, r = nwg & 7;
  int xcd = orig & 7, within = orig >> 3;
  int pos = (xcd < r ? xcd * (q + 1) : r * (q + 1) + (xcd - r) * q) + within;
  bx = pos / gy;
  by = pos % gy;
}

// ---------------- init: h (fp32) = x (fp32) ----------------
__global__ __launch_bounds__(256) void init_h_kernel(const float* __restrict__ x,
                                                     float* __restrict__ h) {
  int i = blockIdx.x * 256 + threadIdx.x;
  reinterpret_cast<f32x4*>(h)[i] = reinterpret_cast<const f32x4*>(x)[i];
}

// ---------------- LayerNorm: fp32 h row -> OUT_T out ----------------
template <typename OUT_T>
__global__ __launch_bounds__(256) void ln_kernel(const float* __restrict__ h,
                                                 const float* __restrict__ g,
                                                 const float* __restrict__ be,
                                                 OUT_T* __restrict__ out) {
  int row = blockIdx.x, tid = threadIdx.x;
  const float* hr = h + (size_t)row * DMODEL;
  float v0 = hr[tid], v1 = hr[tid + 256], v2 = hr[tid + 512];
  float s = v0 + v1 + v2;
  float ss = v0 * v0 + v1 * v1 + v2 * v2;
  for (int off = 32; off; off >>= 1) {
    s += __shfl_down(s, off);
    ss += __shfl_down(ss, off);
  }
  __shared__ float red[8];
  int wid = tid >> 6, lane = tid & 63;
  if (lane == 0) { red[wid] = s; red[4 + wid] = ss; }
  __syncthreads();
  float S = red[0] + red[1] + red[2] + red[3];
  float SS = red[4] + red[5] + red[6] + red[7];
  float mean = S * (1.f / DMODEL);
  float var = SS * (1.f / DMODEL) - mean * mean;
  float rstd = rsqrtf(var + 1e-5f);
  OUT_T* orow = out + (size_t)row * DMODEL;
  orow[tid]       = (OUT_T)((v0 - mean) * rstd * g[tid]       + be[tid]);
  orow[tid + 256] = (OUT_T)((v1 - mean) * rstd * g[tid + 256] + be[tid + 256]);
  orow[tid + 512] = (OUT_T)((v2 - mean) * rstd * g[tid + 512] + be[tid + 512]);
}

// ---------------- transpose body: W fp32 [K][N] tile -> Wt bf16 [N][K] ----------
__device__ __forceinline__ void transpose_tile(const float* __restrict__ W,
                                               bf16_t* __restrict__ Wt,
                                               int K, int N, int n0, int k0) {
  __shared__ alignas(16) bf16_t t[64][72];
  int tid = threadIdx.x;
  int rr = tid / 8, cc8 = tid % 8, cc = cc8 * 8;
#pragma unroll
  for (int it = 0; it < 2; ++it) {
    int k = rr + it * 32;
    const float* src = &W[(size_t)(k0 + k) * N + n0 + cc];
    f32x4 v0 = *reinterpret_cast<const f32x4*>(src);
    f32x4 v1 = *reinterpret_cast<const f32x4*>(src + 4);
    int kx = k ^ (cc8 * 8);
#pragma unroll
    for (int i = 0; i < 4; ++i) t[cc + i][kx] = (bf16_t)v0[i];
#pragma unroll
    for (int i = 0; i < 4; ++i) t[cc + 4 + i][kx] = (bf16_t)v1[i];
  }
  __syncthreads();
#pragma unroll
  for (int it = 0; it < 2; ++it) {
    int n = rr + it * 32;
    int ccx = cc ^ (8 * ((n >> 3) & 7));
    bf16x8 v = *reinterpret_cast<const bf16x8*>(&t[n][ccx]);
    *reinterpret_cast<bf16x8*>(&Wt[(size_t)(n0 + n) * K + k0 + cc]) = v;
  }
}

// per-layer single-weight transpose (fallback path)
__global__ __launch_bounds__(256) void transpose_w(const float* __restrict__ W,
                                                   bf16_t* __restrict__ Wt,
                                                   int K, int N) {
  transpose_tile(W, Wt, K, N, blockIdx.x * 64, blockIdx.y * 64);
}

// all layers x all 4 weights in one dispatch (big-ws path)
__global__ __launch_bounds__(256) void transpose_all(const float* __restrict__ Wqkv,
                                                     const float* __restrict__ Wout,
                                                     const float* __restrict__ W1,
                                                     const float* __restrict__ W2,
                                                     bf16_t* __restrict__ wtall) {
  const int l = blockIdx.y;
  const int t = blockIdx.x;
  bf16_t* wl = wtall + (size_t)l * WT_LAYER;
  if (t < 432) {
    transpose_tile(Wqkv + (size_t)l * DMODEL * QKVD, wl + WT_QKV,
                   DMODEL, QKVD, (t % 36) * 64, (t / 36) * 64);
  } else if (t < 576) {
    int u = t - 432;
    transpose_tile(Wout + (size_t)l * DMODEL * DMODEL, wl + WT_WOUT,
                   DMODEL, DMODEL, (u % 12) * 64, (u / 12) * 64);
  } else if (t < 1152) {
    int u = t - 576;
    transpose_tile(W1 + (size_t)l * DMODEL * DFFN, wl + WT_W1,
                   DMODEL, DFFN, (u % 48) * 64, (u / 48) * 64);
  } else {
    int u = t - 1152;
    transpose_tile(W2 + (size_t)l * DFFN * DMODEL, wl + WT_W2,
                   DFFN, DMODEL, (u % 12) * 64, (u / 12) * 64);
  }
}

// ---------------- GEMM 128x128: minimum 2-phase (T3 recipe), dbuf-2, 32KB LDS ------
// Per iter: STAGE(next) at top -> ds_read cur -> MFMA -> vmcnt(0)+barrier at bottom.
// 5 blocks/CU by LDS. T2 read swizzle retained.
template <int EPI>
__global__ __launch_bounds__(256) void gemm_bt(const bf16_t* __restrict__ A,
                                               const bf16_t* __restrict__ Bt,
                                               int M, int N, int K,
                                               const float* __restrict__ bias,
                                               bf16_t* __restrict__ Cb) {
  __shared__ alignas(16) bf16_t lA[2][128 * 32];
  __shared__ alignas(16) bf16_t lB[2][128 * 32];
  const int tid = threadIdx.x;
  const int lane = tid & 63;
  const int wid = tid >> 6;
  const int wr = wid >> 1, wc = wid & 1;
  int bx, by;
  swz_block(gridDim.x, gridDim.y, bx, by);
  const int brow = by * 128, bcol = bx * 128;

  f32x4 acc[4][4];
#pragma unroll
  for (int i = 0; i < 4; ++i)
#pragma unroll
    for (int j = 0; j < 4; ++j) acc[i][j] = zero4();

  const int arow = tid >> 2;
  const int acol = (((tid & 3) ^ ((tid >> 3) & 3))) * 8;   // inverse-swizzled source chunk
  const bf16_t* aptr = A + (size_t)(brow + arow) * K + acol;
  const bf16_t* bptr = Bt + (size_t)(bcol + arow) * K + acol;
  const int ldsoff = tid * 8;

  const int nk = K / 32;
  const int fro = (lane & 15) * 32 + (((lane >> 4) ^ (((lane & 15) >> 1) & 3))) * 8;

  auto STAGE = [&](int buf, int kt) {
    const bf16_t* a = aptr + kt * 32;
    const bf16_t* b = bptr + kt * 32;
    gload_lds16(a, &lA[buf][ldsoff]);
    gload_lds16(a + (size_t)64 * K, &lA[buf][ldsoff + 2048]);
    gload_lds16(b, &lB[buf][ldsoff]);
    gload_lds16(b + (size_t)64 * K, &lB[buf][ldsoff + 2048]);
  };

  STAGE(0, 0);
  asm volatile("s_waitcnt vmcnt(0)" ::: "memory");
  __builtin_amdgcn_s_barrier();

  for (int kt = 0; kt < nk; ++kt) {
    const int cur = kt & 1;
    if (kt + 1 < nk) STAGE(cur ^ 1, kt + 1);   // full-iteration flight

    bf16x8 af[4], bfr[4];
#pragma unroll
    for (int mi = 0; mi < 4; ++mi)
      af[mi] = *reinterpret_cast<const bf16x8*>(&lA[cur][(wr * 64 + mi * 16) * 32 + fro]);
#pragma unroll
    for (int ni = 0; ni < 4; ++ni)
      bfr[ni] = *reinterpret_cast<const bf16x8*>(&lB[cur][(wc * 64 + ni * 16) * 32 + fro]);
#pragma unroll
    for (int mi = 0; mi < 4; ++mi)
#pragma unroll
      for (int ni = 0; ni < 4; ++ni)
        acc[mi][ni] = __builtin_amdgcn_mfma_f32_16x16x32_bf16(af[mi], bfr[ni], acc[mi][ni], 0, 0, 0);

    if (kt + 1 < nk) {
      asm volatile("s_waitcnt vmcnt(0)" ::: "memory");  // next tile landed (hidden by this iter)
      __builtin_amdgcn_s_barrier();
    }
  }

#pragma unroll
  for (int mi = 0; mi < 4; ++mi) {
    int rowb = brow + wr * 64 + mi * 16 + (lane >> 4) * 4;
#pragma unroll
    for (int ni = 0; ni < 4; ++ni) {
      int col = bcol + wc * 64 + ni * 16 + (lane & 15);
#pragma unroll
      for (int r = 0; r < 4; ++r) {
        float v = acc[mi][ni][r];
        size_t idx = (size_t)(rowb + r) * N + col;
        if (EPI == 0) {
          Cb[idx] = (bf16_t)v;
        } else {
          v += bias[col];
          v = 0.5f * v * (1.0f + erff(v * 0.70710678118f));
          Cb[idx] = (bf16_t)v;
        }
      }
    }
  }
}

// ---------------- GEMM 64x128: minimum 2-phase, dbuf-2, 24KB LDS, fused h+= --------
__global__ __launch_bounds__(256) void gemm_sm(const bf16_t* __restrict__ A,
                                               const bf16_t* __restrict__ Bt,
                                               int M, int N, int K,
                                               const float* __restrict__ bias,
                                               float* __restrict__ hres) {
  __shared__ alignas(16) bf16_t lA[2][64 * 32];
  __shared__ alignas(16) bf16_t lB[2][128 * 32];
  const int tid = threadIdx.x;
  const int lane = tid & 63;
  const int wid = tid >> 6;
  int bx, by;
  swz_block(gridDim.x, gridDim.y, bx, by);
  const int brow = by * 64, bcol = bx * 128;

  f32x4 acc[4][2];
#pragma unroll
  for (int i = 0; i < 4; ++i)
#pragma unroll
    for (int j = 0; j < 2; ++j) acc[i][j] = zero4();

  const int arow = tid >> 2;
  const int acol = (((tid & 3) ^ ((tid >> 3) & 3))) * 8;
  const bf16_t* aptr = A + (size_t)(brow + arow) * K + acol;
  const bf16_t* bptr = Bt + (size_t)(bcol + arow) * K + acol;
  const int ldsoff = tid * 8;

  const int nk = K / 32;
  const int fro = (lane & 15) * 32 + (((lane >> 4) ^ (((lane & 15) >> 1) & 3))) * 8;

  auto STAGE = [&](int buf, int kt) {
    const bf16_t* a = aptr + kt * 32;
    const bf16_t* b = bptr + kt * 32;
    gload_lds16(a, &lA[buf][ldsoff]);
    gload_lds16(b, &lB[buf][ldsoff]);
    gload_lds16(b + (size_t)64 * K, &lB[buf][ldsoff + 2048]);
  };

  STAGE(0, 0);
  asm volatile("s_waitcnt vmcnt(0)" ::: "memory");
  __builtin_amdgcn_s_barrier();

  for (int kt = 0; kt < nk; ++kt) {
    const int cur = kt & 1;
    if (kt + 1 < nk) STAGE(cur ^ 1, kt + 1);

    bf16x8 af[4], bfr[2];
#pragma unroll
    for (int mi = 0; mi < 4; ++mi)
      af[mi] = *reinterpret_cast<const bf16x8*>(&lA[cur][mi * 512 + fro]);
#pragma unroll
    for (int ni = 0; ni < 2; ++ni)
      bfr[ni] = *reinterpret_cast<const bf16x8*>(&lB[cur][(wid * 32 + ni * 16) * 32 + fro]);
#pragma unroll
    for (int mi = 0; mi < 4; ++mi)
#pragma unroll
      for (int ni = 0; ni < 2; ++ni)
        acc[mi][ni] = __builtin_amdgcn_mfma_f32_16x16x32_bf16(af[mi], bfr[ni], acc[mi][ni], 0, 0, 0);

    if (kt + 1 < nk) {
      asm volatile("s_waitcnt vmcnt(0)" ::: "memory");
      __builtin_amdgcn_s_barrier();
    }
  }

#pragma unroll
  for (int mi = 0; mi < 4; ++mi) {
    int rowb = brow + mi * 16 + (lane >> 4) * 4;
#pragma unroll
    for (int ni = 0; ni < 2; ++ni) {
      int col = bcol + wid * 32 + ni * 16 + (lane & 15);
#pragma unroll
      for (int r = 0; r < 4; ++r) {
        float v = acc[mi][ni][r] + bias[col];
        hres[(size_t)(rowb + r) * N + col] += v;
      }
    }
  }
}

// ---------------- Attention (flash-style), one block = (bh, 64 q rows) ----------------
__global__ __launch_bounds__(256) void attn_kernel(const bf16_t* __restrict__ qkv,
                                                   bf16_t* __restrict__ o) {
  const int qb = blockIdx.x;   // 0..15
  const int bh = blockIdx.y;   // 0..47
  const int b = bh / NHEADS, hh = bh % NHEADS;
  const int tid = threadIdx.x;
  const int lane = tid & 63, wid = tid >> 6;

  __shared__ alignas(16) bf16_t lK[2][64][72];
  __shared__ alignas(16) bf16_t lV[2][64][72];   // [d][j ^ 8*((d>>3)&7)]
  __shared__ alignas(16) bf16_t lP[4][16][72];   // wave-private P tiles

  bf16x8 qf[2];
  {
    int q = qb * 64 + wid * 16 + (lane & 15);
    const bf16_t* qrow = qkv + (size_t)(b * NSEQ + q) * QKVD + hh * HD + (lane >> 4) * 8;
    qf[0] = *reinterpret_cast<const bf16x8*>(qrow);
    qf[1] = *reinterpret_cast<const bf16x8*>(qrow + 32);
  }

  const int r = tid / 8;
  const int c = (tid % 8) * 8;
  const int vswz = (c & 0x38);
  const bf16_t* kbase = qkv + (size_t)(b * NSEQ) * QKVD + DMODEL + hh * HD + c;
  const bf16_t* vbase = qkv + (size_t)(b * NSEQ) * QKVD + 2 * DMODEL + hh * HD + c;

  bf16x8 kreg[2], vreg[2];
  auto LOADKV = [&](int j0) {
#pragma unroll
    for (int it = 0; it < 2; ++it) {
      int rr = r + it * 32;
      kreg[it] = *reinterpret_cast<const bf16x8*>(kbase + (size_t)(j0 + rr) * QKVD);
      vreg[it] = *reinterpret_cast<const bf16x8*>(vbase + (size_t)(j0 + rr) * QKVD);
    }
  };
  auto WRITEKV = [&](int buf) {
#pragma unroll
    for (int it = 0; it < 2; ++it) {
      int rr = r + it * 32;
      *reinterpret_cast<bf16x8*>(&lK[buf][rr][c]) = kreg[it];
      int col = rr ^ vswz;
#pragma unroll
      for (int i = 0; i < 8; ++i) lV[buf][c + i][col] = vreg[it][i];
    }
  };

  float m[4], lsum[4];
  f32x4 oacc[4];
#pragma unroll
  for (int rr = 0; rr < 4; ++rr) { m[rr] = -1e30f; lsum[rr] = 0.f; }
#pragma unroll
  for (int df = 0; df < 4; ++df) oacc[df] = zero4();

  LOADKV(0);
  WRITEKV(0);
  __syncthreads();

  for (int jb = 0; jb < 16; ++jb) {
    const int cur = jb & 1;
    if (jb < 15) LOADKV((jb + 1) * 64);

    f32x4 s[4];
    __builtin_amdgcn_s_setprio(1);
#pragma unroll
    for (int jf = 0; jf < 4; ++jf) {
      s[jf] = zero4();
#pragma unroll
      for (int dk = 0; dk < 2; ++dk) {
        bf16x8 kf = *reinterpret_cast<const bf16x8*>(
            &lK[cur][jf * 16 + (lane & 15)][(lane >> 4) * 8 + dk * 32]);
        s[jf] = __builtin_amdgcn_mfma_f32_16x16x32_bf16(qf[dk], kf, s[jf], 0, 0, 0);
      }
    }
    __builtin_amdgcn_s_setprio(0);

    float mx[4];
#pragma unroll
    for (int rr = 0; rr < 4; ++rr) {
      float v = -1e30f;
#pragma unroll
      for (int jf = 0; jf < 4; ++jf) {
        s[jf][rr] = s[jf][rr] * 0.125f;
        v = fmaxf(v, s[jf][rr]);
      }
#pragma unroll
      for (int msk = 1; msk < 16; msk <<= 1) v = fmaxf(v, __shfl_xor(v, msk));
      mx[rr] = v;
    }
    bool upd = (mx[0] > m[0] + 8.f) | (mx[1] > m[1] + 8.f) |
               (mx[2] > m[2] + 8.f) | (mx[3] > m[3] + 8.f);
    if (__any(upd)) {
      float fac[4];
#pragma unroll
      for (int rr = 0; rr < 4; ++rr) {
        float pm = fmaxf(m[rr], mx[rr]);
        fac[rr] = __expf(m[rr] - pm);
        m[rr] = pm;
        lsum[rr] *= fac[rr];
      }
#pragma unroll
      for (int df = 0; df < 4; ++df)
#pragma unroll
        for (int rr = 0; rr < 4; ++rr) oacc[df][rr] = oacc[df][rr] * fac[rr];
    }

    float rs[4] = {0.f, 0.f, 0.f, 0.f};
#pragma unroll
    for (int jf = 0; jf < 4; ++jf) {
#pragma unroll
      for (int rr = 0; rr < 4; ++rr) {
        float pv = __expf(s[jf][rr] - m[rr]);
        rs[rr] += pv;
        lP[wid][(lane >> 4) * 4 + rr][jf * 16 + (lane & 15)] = (bf16_t)pv;
      }
    }
#pragma unroll
    for (int rr = 0; rr < 4; ++rr) {
      float t = rs[rr];
#pragma unroll
      for (int msk = 1; msk < 16; msk <<= 1) t += __shfl_xor(t, msk);
      lsum[rr] += t;
    }

    __syncthreads();

    if (jb < 15) WRITEKV(cur ^ 1);

    __builtin_amdgcn_s_setprio(1);
#pragma unroll
    for (int df = 0; df < 4; ++df) {
      int d = df * 16 + (lane & 15);
      int rsw = (d & 0x38);
#pragma unroll
      for (int js = 0; js < 2; ++js) {
        bf16x8 pf = *reinterpret_cast<const bf16x8*>(
            &lP[wid][lane & 15][(lane >> 4) * 8 + js * 32]);
        bf16x8 vf = *reinterpret_cast<const bf16x8*>(
            &lV[cur][d][((lane >> 4) * 8 + js * 32) ^ rsw]);
        oacc[df] = __builtin_amdgcn_mfma_f32_16x16x32_bf16(pf, vf, oacc[df], 0, 0, 0);
      }
    }
    __builtin_amdgcn_s_setprio(0);

    __syncthreads();
  }

  int q0 = qb * 64 + wid * 16 + (lane >> 4) * 4;
#pragma unroll
  for (int rr = 0; rr < 4; ++rr) {
    float inv = 1.0f / lsum[rr];
#pragma unroll
    for (int df = 0; df < 4; ++df) {
      int col = hh * HD + df * 16 + (lane & 15);
      o[(size_t)(b * NSEQ + q0 + rr) * DMODEL + col] = (bf16_t)(oacc[df][rr] * inv);
    }
  }
}

// ---------------- host launch ----------------
extern "C" void kernel_launch(void* const* d_in, const int* in_sizes, int n_in,
                              void* d_out, int out_size, void* d_ws, size_t ws_size,
                              hipStream_t stream) {
  const float* x    = (const float*)d_in[0];
  const float* Wqkv = (const float*)d_in[1];
  const float* Wout = (const float*)d_in[2];
  const float* bout = (const float*)d_in[3];
  const float* ln1g = (const float*)d_in[4];
  const float* ln1b = (const float*)d_in[5];
  const float* W1   = (const float*)d_in[6];
  const float* b1   = (const float*)d_in[7];
  const float* W2   = (const float*)d_in[8];
  const float* b2   = (const float*)d_in[9];
  const float* ln2g = (const float*)d_in[10];
  const float* ln2b = (const float*)d_in[11];
  const float* lnfg = (const float*)d_in[12];
  const float* lnfb = (const float*)d_in[13];

  char* p = (char*)d_ws;
  float*  h   = (float*)p;
  bf16_t* xn  = (bf16_t*)(p + 12582912);
  bf16_t* big = (bf16_t*)(p + 18874368);
  bf16_t* wt  = (bf16_t*)(p + 44040192);
  bf16_t* attno = xn;
  bf16_t* qkvb  = big;
  bf16_t* ffh   = big;

  const bool bigws = ws_size >= 157286400ull;

  init_h_kernel<<<TOK * DMODEL / 1024, 256, 0, stream>>>(x, h);
  if (bigws)
    transpose_all<<<dim3(1728, NLAYER), 256, 0, stream>>>(Wqkv, Wout, W1, W2, wt);

  for (int l = 0; l < NLAYER; ++l) {
    const bf16_t* wl = wt + (size_t)l * WT_LAYER;
    const bf16_t* qkv_t  = bigws ? wl + WT_QKV  : wt;
    const bf16_t* wout_t = bigws ? wl + WT_WOUT : wt;
    const bf16_t* w1_t   = bigws ? wl + WT_W1   : wt;
    const bf16_t* w2_t   = bigws ? wl + WT_W2   : wt;

    // 1) LN1 -> xn ; QKV GEMM -> qkvb
    if (!bigws)
      transpose_w<<<dim3(QKVD / 64, DMODEL / 64), 256, 0, stream>>>(
          Wqkv + (size_t)l * DMODEL * QKVD, wt, DMODEL, QKVD);
    ln_kernel<bf16_t><<<TOK, 256, 0, stream>>>(h, ln1g + l * DMODEL, ln1b + l * DMODEL, xn);
    gemm_bt<0><<<dim3(QKVD / 128, TOK / 128), 256, 0, stream>>>(
        xn, qkv_t, TOK, QKVD, DMODEL, nullptr, qkvb);

    // 2) attention -> attno (aliases xn, xn is dead)
    attn_kernel<<<dim3(16, 48), 256, 0, stream>>>(qkvb, attno);

    // 3) out-proj, h += attno @ Wout + bout  (64x128 tiles, 384 blocks)
    if (!bigws)
      transpose_w<<<dim3(DMODEL / 64, DMODEL / 64), 256, 0, stream>>>(
          Wout + (size_t)l * DMODEL * DMODEL, wt, DMODEL, DMODEL);
    gemm_sm<<<dim3(DMODEL / 128, TOK / 64), 256, 0, stream>>>(
        attno, wout_t, TOK, DMODEL, DMODEL, bout + l * DMODEL, h);

    // 4) LN2 -> xn ; FF1 (gelu) -> ffh
    if (!bigws)
      transpose_w<<<dim3(DFFN / 64, DMODEL / 64), 256, 0, stream>>>(
          W1 + (size_t)l * DMODEL * DFFN, wt, DMODEL, DFFN);
    ln_kernel<bf16_t><<<TOK, 256, 0, stream>>>(h, ln2g + l * DMODEL, ln2b + l * DMODEL, xn);
    gemm_bt<1><<<dim3(DFFN / 128, TOK / 128), 256, 0, stream>>>(
        xn, w1_t, TOK, DFFN, DMODEL, b1 + l * DFFN, ffh);

    // 5) FF2, h += ffh @ W2 + b2  (64x128 tiles, 384 blocks)
    if (!bigws)
      transpose_w<<<dim3(DMODEL / 64, DFFN / 64), 256, 0, stream>>>(
          W2 + (size_t)l * DFFN * DMODEL, wt, DFFN, DMODEL);
    gemm_sm<<<dim3(DMODEL / 128, TOK / 64), 256, 0, stream>>>(
        ffh, w2_t, TOK, DMODEL, DFFN, b2 + l * DMODEL, h);
  }

  ln_kernel<float><<<TOK, 256, 0, stream>>>(h, lnfg, lnfb, (float*)d_out);
}

// Round 16
// 1671.552 us; speedup vs baseline: 1.0514x; 1.0514x over previous
//
#include <hip/hip_runtime.h>

#define TOK 4096
#define DMODEL 768
#define NSEQ 1024
#define NHEADS 12
#define HD 64
#define DFFN 3072
#define NLAYER 8
#define QKVD 2304

// per-layer W^T element offsets in the all-layers region
#define WT_QKV  0
#define WT_WOUT 1769472
#define WT_W1   2359296
#define WT_W2   4718592
#define WT_LAYER 7077888   // elements per layer (14,155,776 B)

typedef __bf16 bf16_t;
typedef __bf16 bf16x8 __attribute__((ext_vector_type(8)));
typedef float f32x4 __attribute__((ext_vector_type(4)));

__device__ __forceinline__ f32x4 zero4() { f32x4 z = {0.f, 0.f, 0.f, 0.f}; return z; }

__device__ __forceinline__ void gload_lds16(const void* g, void* l) {
  __builtin_amdgcn_global_load_lds((__attribute__((address_space(1))) void*)(g),
                                   (__attribute__((address_space(3))) void*)(l),
                                   16, 0, 0);
}

// XCD-aware bijective chunked remap (m204), x-major output ordering.
__device__ __forceinline__ void swz_block(int gx, int gy, int& bx, int& by) {
  int nwg = gx * gy;
  int orig = blockIdx.y * gx + blockIdx.x;
  int q = nwg >> 3, r = nwg & 7;
  int xcd = orig & 7, within = orig >> 3;
  int pos = (xcd < r ? xcd * (q + 1) : r * (q + 1) + (xcd - r) * q) + within;
  bx = pos / gy;
  by = pos % gy;
}

// ---------------- init: h (fp32) = x (fp32) ----------------
__global__ __launch_bounds__(256) void init_h_kernel(const float* __restrict__ x,
                                                     float* __restrict__ h) {
  int i = blockIdx.x * 256 + threadIdx.x;
  reinterpret_cast<f32x4*>(h)[i] = reinterpret_cast<const f32x4*>(x)[i];
}

// ---------------- LayerNorm: fp32 h row -> OUT_T out ----------------
template <typename OUT_T>
__global__ __launch_bounds__(256) void ln_kernel(const float* __restrict__ h,
                                                 const float* __restrict__ g,
                                                 const float* __restrict__ be,
                                                 OUT_T* __restrict__ out) {
  int row = blockIdx.x, tid = threadIdx.x;
  const float* hr = h + (size_t)row * DMODEL;
  float v0 = hr[tid], v1 = hr[tid + 256], v2 = hr[tid + 512];
  float s = v0 + v1 + v2;
  float ss = v0 * v0 + v1 * v1 + v2 * v2;
  for (int off = 32; off; off >>= 1) {
    s += __shfl_down(s, off);
    ss += __shfl_down(ss, off);
  }
  __shared__ float red[8];
  int wid = tid >> 6, lane = tid & 63;
  if (lane == 0) { red[wid] = s; red[4 + wid] = ss; }
  __syncthreads();
  float S = red[0] + red[1] + red[2] + red[3];
  float SS = red[4] + red[5] + red[6] + red[7];
  float mean = S * (1.f / DMODEL);
  float var = SS * (1.f / DMODEL) - mean * mean;
  float rstd = rsqrtf(var + 1e-5f);
  OUT_T* orow = out + (size_t)row * DMODEL;
  orow[tid]       = (OUT_T)((v0 - mean) * rstd * g[tid]       + be[tid]);
  orow[tid + 256] = (OUT_T)((v1 - mean) * rstd * g[tid + 256] + be[tid + 256]);
  orow[tid + 512] = (OUT_T)((v2 - mean) * rstd * g[tid + 512] + be[tid + 512]);
}

// ---------------- transpose body: W fp32 [K][N] tile -> Wt bf16 [N][K] ----------
__device__ __forceinline__ void transpose_tile(const float* __restrict__ W,
                                               bf16_t* __restrict__ Wt,
                                               int K, int N, int n0, int k0) {
  __shared__ alignas(16) bf16_t t[64][72];
  int tid = threadIdx.x;
  int rr = tid / 8, cc8 = tid % 8, cc = cc8 * 8;
#pragma unroll
  for (int it = 0; it < 2; ++it) {
    int k = rr + it * 32;
    const float* src = &W[(size_t)(k0 + k) * N + n0 + cc];
    f32x4 v0 = *reinterpret_cast<const f32x4*>(src);
    f32x4 v1 = *reinterpret_cast<const f32x4*>(src + 4);
    int kx = k ^ (cc8 * 8);
#pragma unroll
    for (int i = 0; i < 4; ++i) t[cc + i][kx] = (bf16_t)v0[i];
#pragma unroll
    for (int i = 0; i < 4; ++i) t[cc + 4 + i][kx] = (bf16_t)v1[i];
  }
  __syncthreads();
#pragma unroll
  for (int it = 0; it < 2; ++it) {
    int n = rr + it * 32;
    int ccx = cc ^ (8 * ((n >> 3) & 7));
    bf16x8 v = *reinterpret_cast<const bf16x8*>(&t[n][ccx]);
    *reinterpret_cast<bf16x8*>(&Wt[(size_t)(n0 + n) * K + k0 + cc]) = v;
  }
}

// per-layer single-weight transpose (fallback path)
__global__ __launch_bounds__(256) void transpose_w(const float* __restrict__ W,
                                                   bf16_t* __restrict__ Wt,
                                                   int K, int N) {
  transpose_tile(W, Wt, K, N, blockIdx.x * 64, blockIdx.y * 64);
}

// all layers x all 4 weights in one dispatch (big-ws path)
__global__ __launch_bounds__(256) void transpose_all(const float* __restrict__ Wqkv,
                                                     const float* __restrict__ Wout,
                                                     const float* __restrict__ W1,
                                                     const float* __restrict__ W2,
                                                     bf16_t* __restrict__ wtall) {
  const int l = blockIdx.y;
  const int t = blockIdx.x;
  bf16_t* wl = wtall + (size_t)l * WT_LAYER;
  if (t < 432) {
    transpose_tile(Wqkv + (size_t)l * DMODEL * QKVD, wl + WT_QKV,
                   DMODEL, QKVD, (t % 36) * 64, (t / 36) * 64);
  } else if (t < 576) {
    int u = t - 432;
    transpose_tile(Wout + (size_t)l * DMODEL * DMODEL, wl + WT_WOUT,
                   DMODEL, DMODEL, (u % 12) * 64, (u / 12) * 64);
  } else if (t < 1152) {
    int u = t - 576;
    transpose_tile(W1 + (size_t)l * DMODEL * DFFN, wl + WT_W1,
                   DMODEL, DFFN, (u % 48) * 64, (u / 48) * 64);
  } else {
    int u = t - 1152;
    transpose_tile(W2 + (size_t)l * DFFN * DMODEL, wl + WT_W2,
                   DFFN, DMODEL, (u % 12) * 64, (u / 12) * 64);
  }
}

// ---------------- GEMM 128x128: C = A @ Bt^T, depth-2 pipeline + T2 LDS swizzle ------
template <int EPI>
__global__ __launch_bounds__(256) void gemm_bt(const bf16_t* __restrict__ A,
                                               const bf16_t* __restrict__ Bt,
                                               int M, int N, int K,
                                               const float* __restrict__ bias,
                                               bf16_t* __restrict__ Cb) {
  __shared__ alignas(16) bf16_t lA[3][128 * 32];
  __shared__ alignas(16) bf16_t lB[3][128 * 32];
  const int tid = threadIdx.x;
  const int lane = tid & 63;
  const int wid = tid >> 6;
  const int wr = wid >> 1, wc = wid & 1;
  int bx, by;
  swz_block(gridDim.x, gridDim.y, bx, by);
  const int brow = by * 128, bcol = bx * 128;

  f32x4 acc[4][4];
#pragma unroll
  for (int i = 0; i < 4; ++i)
#pragma unroll
    for (int j = 0; j < 4; ++j) acc[i][j] = zero4();

  const int arow = tid >> 2;
  const int acol = (((tid & 3) ^ ((tid >> 3) & 3))) * 8;   // inverse-swizzled source chunk
  const bf16_t* aptr = A + (size_t)(brow + arow) * K + acol;
  const bf16_t* bptr = Bt + (size_t)(bcol + arow) * K + acol;
  const int ldsoff = tid * 8;

  const int nk = K / 32;
  const int fro = (lane & 15) * 32 + (((lane >> 4) ^ (((lane & 15) >> 1) & 3))) * 8;

  auto STAGE = [&](int buf, int kt) {
    const bf16_t* a = aptr + kt * 32;
    const bf16_t* b = bptr + kt * 32;
    gload_lds16(a, &lA[buf][ldsoff]);
    gload_lds16(a + (size_t)64 * K, &lA[buf][ldsoff + 2048]);
    gload_lds16(b, &lB[buf][ldsoff]);
    gload_lds16(b + (size_t)64 * K, &lB[buf][ldsoff + 2048]);
  };

  auto BODY = [&](int kt) {
    const int cur = kt % 3;
    __builtin_amdgcn_s_barrier();
    bf16x8 af[4], bfr[4];
#pragma unroll
    for (int mi = 0; mi < 4; ++mi)
      af[mi] = *reinterpret_cast<const bf16x8*>(&lA[cur][(wr * 64 + mi * 16) * 32 + fro]);
#pragma unroll
    for (int ni = 0; ni < 4; ++ni)
      bfr[ni] = *reinterpret_cast<const bf16x8*>(&lB[cur][(wc * 64 + ni * 16) * 32 + fro]);
    if (kt + 2 < nk) STAGE((kt + 2) % 3, kt + 2);
#pragma unroll
    for (int mi = 0; mi < 4; ++mi)
#pragma unroll
      for (int ni = 0; ni < 4; ++ni)
        acc[mi][ni] = __builtin_amdgcn_mfma_f32_16x16x32_bf16(af[mi], bfr[ni], acc[mi][ni], 0, 0, 0);
  };

  STAGE(0, 0);
  STAGE(1, 1);
  for (int kt = 0; kt < nk; ++kt) {
    if (kt < nk - 1) asm volatile("s_waitcnt vmcnt(4)" ::: "memory");
    else             asm volatile("s_waitcnt vmcnt(0)" ::: "memory");
    BODY(kt);
  }

#pragma unroll
  for (int mi = 0; mi < 4; ++mi) {
    int rowb = brow + wr * 64 + mi * 16 + (lane >> 4) * 4;
#pragma unroll
    for (int ni = 0; ni < 4; ++ni) {
      int col = bcol + wc * 64 + ni * 16 + (lane & 15);
#pragma unroll
      for (int r = 0; r < 4; ++r) {
        float v = acc[mi][ni][r];
        size_t idx = (size_t)(rowb + r) * N + col;
        if (EPI == 0) {
          Cb[idx] = (bf16_t)v;
        } else {
          v += bias[col];
          v = 0.5f * v * (1.0f + erff(v * 0.70710678118f));
          Cb[idx] = (bf16_t)v;
        }
      }
    }
  }
}

// ---------------- GEMM 64x128 (N=768 shapes): depth-3 pipeline + T2 swizzle ---------
__global__ __launch_bounds__(256) void gemm_sm(const bf16_t* __restrict__ A,
                                               const bf16_t* __restrict__ Bt,
                                               int M, int N, int K,
                                               const float* __restrict__ bias,
                                               float* __restrict__ hres) {
  __shared__ alignas(16) bf16_t lA[4][64 * 32];
  __shared__ alignas(16) bf16_t lB[4][128 * 32];
  const int tid = threadIdx.x;
  const int lane = tid & 63;
  const int wid = tid >> 6;
  int bx, by;
  swz_block(gridDim.x, gridDim.y, bx, by);
  const int brow = by * 64, bcol = bx * 128;

  f32x4 acc[4][2];
#pragma unroll
  for (int i = 0; i < 4; ++i)
#pragma unroll
    for (int j = 0; j < 2; ++j) acc[i][j] = zero4();

  const int arow = tid >> 2;
  const int acol = (((tid & 3) ^ ((tid >> 3) & 3))) * 8;
  const bf16_t* aptr = A + (size_t)(brow + arow) * K + acol;
  const bf16_t* bptr = Bt + (size_t)(bcol + arow) * K + acol;
  const int ldsoff = tid * 8;

  const int nk = K / 32;
  const int fro = (lane & 15) * 32 + (((lane >> 4) ^ (((lane & 15) >> 1) & 3))) * 8;

  auto STAGE = [&](int buf, int kt) {
    const bf16_t* a = aptr + kt * 32;
    const bf16_t* b = bptr + kt * 32;
    gload_lds16(a, &lA[buf][ldsoff]);
    gload_lds16(b, &lB[buf][ldsoff]);
    gload_lds16(b + (size_t)64 * K, &lB[buf][ldsoff + 2048]);
  };

  auto BODY = [&](int kt) {
    const int cur = kt & 3;
    __builtin_amdgcn_s_barrier();
    bf16x8 af[4], bfr[2];
#pragma unroll
    for (int mi = 0; mi < 4; ++mi)
      af[mi] = *reinterpret_cast<const bf16x8*>(&lA[cur][mi * 512 + fro]);
#pragma unroll
    for (int ni = 0; ni < 2; ++ni)
      bfr[ni] = *reinterpret_cast<const bf16x8*>(&lB[cur][(wid * 32 + ni * 16) * 32 + fro]);
    if (kt + 3 < nk) STAGE((kt + 3) & 3, kt + 3);
#pragma unroll
    for (int mi = 0; mi < 4; ++mi)
#pragma unroll
      for (int ni = 0; ni < 2; ++ni)
        acc[mi][ni] = __builtin_amdgcn_mfma_f32_16x16x32_bf16(af[mi], bfr[ni], acc[mi][ni], 0, 0, 0);
  };

  STAGE(0, 0);
  STAGE(1, 1);
  STAGE(2, 2);
  for (int kt = 0; kt < nk; ++kt) {
    if (kt < nk - 2)       asm volatile("s_waitcnt vmcnt(6)" ::: "memory");
    else if (kt == nk - 2) asm volatile("s_waitcnt vmcnt(3)" ::: "memory");
    else                   asm volatile("s_waitcnt vmcnt(0)" ::: "memory");
    BODY(kt);
  }

#pragma unroll
  for (int mi = 0; mi < 4; ++mi) {
    int rowb = brow + mi * 16 + (lane >> 4) * 4;
#pragma unroll
    for (int ni = 0; ni < 2; ++ni) {
      int col = bcol + wid * 32 + ni * 16 + (lane & 15);
#pragma unroll
      for (int r = 0; r < 4; ++r) {
        float v = acc[mi][ni][r] + bias[col];
        hres[(size_t)(rowb + r) * N + col] += v;
      }
    }
  }
}

// ---------------- Attention (flash-style), one block = (bh, 64 q rows) ----------------
__global__ __launch_bounds__(256) void attn_kernel(const bf16_t* __restrict__ qkv,
                                                   bf16_t* __restrict__ o) {
  const int qb = blockIdx.x;   // 0..15
  const int bh = blockIdx.y;   // 0..47
  const int b = bh / NHEADS, hh = bh % NHEADS;
  const int tid = threadIdx.x;
  const int lane = tid & 63, wid = tid >> 6;

  __shared__ alignas(16) bf16_t lK[2][64][72];
  __shared__ alignas(16) bf16_t lV[2][64][72];   // [d][j ^ 8*((d>>3)&7)]
  __shared__ alignas(16) bf16_t lP[4][16][72];   // wave-private P tiles

  bf16x8 qf[2];
  {
    int q = qb * 64 + wid * 16 + (lane & 15);
    const bf16_t* qrow = qkv + (size_t)(b * NSEQ + q) * QKVD + hh * HD + (lane >> 4) * 8;
    qf[0] = *reinterpret_cast<const bf16x8*>(qrow);
    qf[1] = *reinterpret_cast<const bf16x8*>(qrow + 32);
  }

  const int r = tid / 8;
  const int c = (tid % 8) * 8;
  const int vswz = (c & 0x38);
  const bf16_t* kbase = qkv + (size_t)(b * NSEQ) * QKVD + DMODEL + hh * HD + c;
  const bf16_t* vbase = qkv + (size_t)(b * NSEQ) * QKVD + 2 * DMODEL + hh * HD + c;

  bf16x8 kreg[2], vreg[2];
  auto LOADKV = [&](int j0) {
#pragma unroll
    for (int it = 0; it < 2; ++it) {
      int rr = r + it * 32;
      kreg[it] = *reinterpret_cast<const bf16x8*>(kbase + (size_t)(j0 + rr) * QKVD);
      vreg[it] = *reinterpret_cast<const bf16x8*>(vbase + (size_t)(j0 + rr) * QKVD);
    }
  };
  auto WRITEKV = [&](int buf) {
#pragma unroll
    for (int it = 0; it < 2; ++it) {
      int rr = r + it * 32;
      *reinterpret_cast<bf16x8*>(&lK[buf][rr][c]) = kreg[it];
      int col = rr ^ vswz;
#pragma unroll
      for (int i = 0; i < 8; ++i) lV[buf][c + i][col] = vreg[it][i];
    }
  };

  float m[4], lsum[4];
  f32x4 oacc[4];
#pragma unroll
  for (int rr = 0; rr < 4; ++rr) { m[rr] = -1e30f; lsum[rr] = 0.f; }
#pragma unroll
  for (int df = 0; df < 4; ++df) oacc[df] = zero4();

  LOADKV(0);
  WRITEKV(0);
  __syncthreads();

  for (int jb = 0; jb < 16; ++jb) {
    const int cur = jb & 1;
    if (jb < 15) LOADKV((jb + 1) * 64);

    f32x4 s[4];
    __builtin_amdgcn_s_setprio(1);
#pragma unroll
    for (int jf = 0; jf < 4; ++jf) {
      s[jf] = zero4();
#pragma unroll
      for (int dk = 0; dk < 2; ++dk) {
        bf16x8 kf = *reinterpret_cast<const bf16x8*>(
            &lK[cur][jf * 16 + (lane & 15)][(lane >> 4) * 8 + dk * 32]);
        s[jf] = __builtin_amdgcn_mfma_f32_16x16x32_bf16(qf[dk], kf, s[jf], 0, 0, 0);
      }
    }
    __builtin_amdgcn_s_setprio(0);

    float mx[4];
#pragma unroll
    for (int rr = 0; rr < 4; ++rr) {
      float v = -1e30f;
#pragma unroll
      for (int jf = 0; jf < 4; ++jf) {
        s[jf][rr] = s[jf][rr] * 0.125f;
        v = fmaxf(v, s[jf][rr]);
      }
#pragma unroll
      for (int msk = 1; msk < 16; msk <<= 1) v = fmaxf(v, __shfl_xor(v, msk));
      mx[rr] = v;
    }
    bool upd = (mx[0] > m[0] + 8.f) | (mx[1] > m[1] + 8.f) |
               (mx[2] > m[2] + 8.f) | (mx[3] > m[3] + 8.f);
    if (__any(upd)) {
      float fac[4];
#pragma unroll
      for (int rr = 0; rr < 4; ++rr) {
        float pm = fmaxf(m[rr], mx[rr]);
        fac[rr] = __expf(m[rr] - pm);
        m[rr] = pm;
        lsum[rr] *= fac[rr];
      }
#pragma unroll
      for (int df = 0; df < 4; ++df)
#pragma unroll
        for (int rr = 0; rr < 4; ++rr) oacc[df][rr] = oacc[df][rr] * fac[rr];
    }

    float rs[4] = {0.f, 0.f, 0.f, 0.f};
#pragma unroll
    for (int jf = 0; jf < 4; ++jf) {
#pragma unroll
      for (int rr = 0; rr < 4; ++rr) {
        float pv = __expf(s[jf][rr] - m[rr]);
        rs[rr] += pv;
        lP[wid][(lane >> 4) * 4 + rr][jf * 16 + (lane & 15)] = (bf16_t)pv;
      }
    }
#pragma unroll
    for (int rr = 0; rr < 4; ++rr) {
      float t = rs[rr];
#pragma unroll
      for (int msk = 1; msk < 16; msk <<= 1) t += __shfl_xor(t, msk);
      lsum[rr] += t;
    }

    __syncthreads();

    if (jb < 15) WRITEKV(cur ^ 1);

    __builtin_amdgcn_s_setprio(1);
#pragma unroll
    for (int df = 0; df < 4; ++df) {
      int d = df * 16 + (lane & 15);
      int rsw = (d & 0x38);
#pragma unroll
      for (int js = 0; js < 2; ++js) {
        bf16x8 pf = *reinterpret_cast<const bf16x8*>(
            &lP[wid][lane & 15][(lane >> 4) * 8 + js * 32]);
        bf16x8 vf = *reinterpret_cast<const bf16x8*>(
            &lV[cur][d][((lane >> 4) * 8 + js * 32) ^ rsw]);
        oacc[df] = __builtin_amdgcn_mfma_f32_16x16x32_bf16(pf, vf, oacc[df], 0, 0, 0);
      }
    }
    __builtin_amdgcn_s_setprio(0);

    __syncthreads();
  }

  int q0 = qb * 64 + wid * 16 + (lane >> 4) * 4;
#pragma unroll
  for (int rr = 0; rr < 4; ++rr) {
    float inv = 1.0f / lsum[rr];
#pragma unroll
    for (int df = 0; df < 4; ++df) {
      int col = hh * HD + df * 16 + (lane & 15);
      o[(size_t)(b * NSEQ + q0 + rr) * DMODEL + col] = (bf16_t)(oacc[df][rr] * inv);
    }
  }
}

// ---------------- host launch ----------------
extern "C" void kernel_launch(void* const* d_in, const int* in_sizes, int n_in,
                              void* d_out, int out_size, void* d_ws, size_t ws_size,
                              hipStream_t stream) {
  const float* x    = (const float*)d_in[0];
  const float* Wqkv = (const float*)d_in[1];
  const float* Wout = (const float*)d_in[2];
  const float* bout = (const float*)d_in[3];
  const float* ln1g = (const float*)d_in[4];
  const float* ln1b = (const float*)d_in[5];
  const float* W1   = (const float*)d_in[6];
  const float* b1   = (const float*)d_in[7];
  const float* W2   = (const float*)d_in[8];
  const float* b2   = (const float*)d_in[9];
  const float* ln2g = (const float*)d_in[10];
  const float* ln2b = (const float*)d_in[11];
  const float* lnfg = (const float*)d_in[12];
  const float* lnfb = (const float*)d_in[13];

  char* p = (char*)d_ws;
  float*  h   = (float*)p;
  bf16_t* xn  = (bf16_t*)(p + 12582912);
  bf16_t* big = (bf16_t*)(p + 18874368);
  bf16_t* wt  = (bf16_t*)(p + 44040192);
  bf16_t* attno = xn;
  bf16_t* qkvb  = big;
  bf16_t* ffh   = big;

  const bool bigws = ws_size >= 157286400ull;

  init_h_kernel<<<TOK * DMODEL / 1024, 256, 0, stream>>>(x, h);
  if (bigws)
    transpose_all<<<dim3(1728, NLAYER), 256, 0, stream>>>(Wqkv, Wout, W1, W2, wt);

  for (int l = 0; l < NLAYER; ++l) {
    const bf16_t* wl = wt + (size_t)l * WT_LAYER;
    const bf16_t* qkv_t  = bigws ? wl + WT_QKV  : wt;
    const bf16_t* wout_t = bigws ? wl + WT_WOUT : wt;
    const bf16_t* w1_t   = bigws ? wl + WT_W1   : wt;
    const bf16_t* w2_t   = bigws ? wl + WT_W2   : wt;

    // 1) LN1 -> xn ; QKV GEMM -> qkvb
    if (!bigws)
      transpose_w<<<dim3(QKVD / 64, DMODEL / 64), 256, 0, stream>>>(
          Wqkv + (size_t)l * DMODEL * QKVD, wt, DMODEL, QKVD);
    ln_kernel<bf16_t><<<TOK, 256, 0, stream>>>(h, ln1g + l * DMODEL, ln1b + l * DMODEL, xn);
    gemm_bt<0><<<dim3(QKVD / 128, TOK / 128), 256, 0, stream>>>(
        xn, qkv_t, TOK, QKVD, DMODEL, nullptr, qkvb);

    // 2) attention -> attno (aliases xn, xn is dead)
    attn_kernel<<<dim3(16, 48), 256, 0, stream>>>(qkvb, attno);

    // 3) out-proj, h += attno @ Wout + bout  (64x128 tiles, 384 blocks)
    if (!bigws)
      transpose_w<<<dim3(DMODEL / 64, DMODEL / 64), 256, 0, stream>>>(
          Wout + (size_t)l * DMODEL * DMODEL, wt, DMODEL, DMODEL);
    gemm_sm<<<dim3(DMODEL / 128, TOK / 64), 256, 0, stream>>>(
        attno, wout_t, TOK, DMODEL, DMODEL, bout + l * DMODEL, h);

    // 4) LN2 -> xn ; FF1 (gelu) -> ffh
    if (!bigws)
      transpose_w<<<dim3(DFFN / 64, DMODEL / 64), 256, 0, stream>>>(
          W1 + (size_t)l * DMODEL * DFFN, wt, DMODEL, DFFN);
    ln_kernel<bf16_t><<<TOK, 256, 0, stream>>>(h, ln2g + l * DMODEL, ln2b + l * DMODEL, xn);
    gemm_bt<1><<<dim3(DFFN / 128, TOK / 128), 256, 0, stream>>>(
        xn, w1_t, TOK, DFFN, DMODEL, b1 + l * DFFN, ffh);

    // 5) FF2, h += ffh @ W2 + b2  (64x128 tiles, 384 blocks)
    if (!bigws)
      transpose_w<<<dim3(DMODEL / 64, DFFN / 64), 256, 0, stream>>>(
          W2 + (size_t)l * DFFN * DMODEL, wt, DFFN, DMODEL);
    gemm_sm<<<dim3(DMODEL / 128, TOK / 64), 256, 0, stream>>>(
        ffh, w2_t, TOK, DMODEL, DFFN, b2 + l * DMODEL, h);
  }

  ln_kernel<float><<<TOK, 256, 0, stream>>>(h, lnfg, lnfb, (float*)d_out);
}

// Round 17
// 1663.903 us; speedup vs baseline: 1.0562x; 1.0046x over previous
//
#include <hip/hip_runtime.h>

#define TOK 4096
#define DMODEL 768
#define NSEQ 1024
#define NHEADS 12
#define HD 64
#define DFFN 3072
#define NLAYER 8
#define QKVD 2304

// per-layer W^T element offsets in the all-layers region
#define WT_QKV  0
#define WT_WOUT 1769472
#define WT_W1   2359296
#define WT_W2   4718592
#define WT_LAYER 7077888   // elements per layer (14,155,776 B)

typedef __bf16 bf16_t;
typedef __bf16 bf16x8 __attribute__((ext_vector_type(8)));
typedef float f32x4 __attribute__((ext_vector_type(4)));

__device__ __forceinline__ f32x4 zero4() { f32x4 z = {0.f, 0.f, 0.f, 0.f}; return z; }

__device__ __forceinline__ void gload_lds16(const void* g, void* l) {
  __builtin_amdgcn_global_load_lds((__attribute__((address_space(1))) void*)(g),
                                   (__attribute__((address_space(3))) void*)(l),
                                   16, 0, 0);
}

// XCD-aware bijective chunked remap (m204), x-major output ordering.
__device__ __forceinline__ void swz_block(int gx, int gy, int& bx, int& by) {
  int nwg = gx * gy;
  int orig = blockIdx.y * gx + blockIdx.x;
  int q = nwg >> 3, r = nwg & 7;
  int xcd = orig & 7, within = orig >> 3;
  int pos = (xcd < r ? xcd * (q + 1) : r * (q + 1) + (xcd - r) * q) + within;
  bx = pos / gy;
  by = pos % gy;
}

// ---------------- init: h (fp32) = x (fp32) ----------------
__global__ __launch_bounds__(256) void init_h_kernel(const float* __restrict__ x,
                                                     float* __restrict__ h) {
  int i = blockIdx.x * 256 + threadIdx.x;
  reinterpret_cast<f32x4*>(h)[i] = reinterpret_cast<const f32x4*>(x)[i];
}

// ---------------- LayerNorm: fp32 h row -> OUT_T out ----------------
template <typename OUT_T>
__global__ __launch_bounds__(256) void ln_kernel(const float* __restrict__ h,
                                                 const float* __restrict__ g,
                                                 const float* __restrict__ be,
                                                 OUT_T* __restrict__ out) {
  int row = blockIdx.x, tid = threadIdx.x;
  const float* hr = h + (size_t)row * DMODEL;
  float v0 = hr[tid], v1 = hr[tid + 256], v2 = hr[tid + 512];
  float s = v0 + v1 + v2;
  float ss = v0 * v0 + v1 * v1 + v2 * v2;
  for (int off = 32; off; off >>= 1) {
    s += __shfl_down(s, off);
    ss += __shfl_down(ss, off);
  }
  __shared__ float red[8];
  int wid = tid >> 6, lane = tid & 63;
  if (lane == 0) { red[wid] = s; red[4 + wid] = ss; }
  __syncthreads();
  float S = red[0] + red[1] + red[2] + red[3];
  float SS = red[4] + red[5] + red[6] + red[7];
  float mean = S * (1.f / DMODEL);
  float var = SS * (1.f / DMODEL) - mean * mean;
  float rstd = rsqrtf(var + 1e-5f);
  OUT_T* orow = out + (size_t)row * DMODEL;
  orow[tid]       = (OUT_T)((v0 - mean) * rstd * g[tid]       + be[tid]);
  orow[tid + 256] = (OUT_T)((v1 - mean) * rstd * g[tid + 256] + be[tid + 256]);
  orow[tid + 512] = (OUT_T)((v2 - mean) * rstd * g[tid + 512] + be[tid + 512]);
}

// ---------------- transpose 64x64 tile (fallback path only) ----------------
__device__ __forceinline__ void transpose_tile(const float* __restrict__ W,
                                               bf16_t* __restrict__ Wt,
                                               int K, int N, int n0, int k0) {
  __shared__ alignas(16) bf16_t t[64][72];
  int tid = threadIdx.x;
  int rr = tid / 8, cc8 = tid % 8, cc = cc8 * 8;
#pragma unroll
  for (int it = 0; it < 2; ++it) {
    int k = rr + it * 32;
    const float* src = &W[(size_t)(k0 + k) * N + n0 + cc];
    f32x4 v0 = *reinterpret_cast<const f32x4*>(src);
    f32x4 v1 = *reinterpret_cast<const f32x4*>(src + 4);
    int kx = k ^ (cc8 * 8);
#pragma unroll
    for (int i = 0; i < 4; ++i) t[cc + i][kx] = (bf16_t)v0[i];
#pragma unroll
    for (int i = 0; i < 4; ++i) t[cc + 4 + i][kx] = (bf16_t)v1[i];
  }
  __syncthreads();
#pragma unroll
  for (int it = 0; it < 2; ++it) {
    int n = rr + it * 32;
    int ccx = cc ^ (8 * ((n >> 3) & 7));
    bf16x8 v = *reinterpret_cast<const bf16x8*>(&t[n][ccx]);
    *reinterpret_cast<bf16x8*>(&Wt[(size_t)(n0 + n) * K + k0 + cc]) = v;
  }
}

__global__ __launch_bounds__(256) void transpose_w(const float* __restrict__ W,
                                                   bf16_t* __restrict__ Wt,
                                                   int K, int N) {
  transpose_tile(W, Wt, K, N, blockIdx.x * 64, blockIdx.y * 64);
}

// ---------------- transpose 128x128 tile: 512B reads / 256B writes ----------------
// element (k,n) stored at t[n][k ^ 8*((n>>3)&15)] (bijective on [0,128), 8-block order kept)
__device__ __forceinline__ void transpose_tile128(const float* __restrict__ W,
                                                  bf16_t* __restrict__ Wt,
                                                  int K, int N, int n0, int k0) {
  __shared__ alignas(16) bf16_t t[128][136];
  const int tid = threadIdx.x;
  // read phase: k-row = (tid>>5) + 8*pass, n-chunk = (tid&31)*4  (512B/row)
  const int kr = tid >> 5;
  const int nc = (tid & 31) * 4;
  const int phi_r = 8 * ((nc >> 3) & 15);   // constant over nc..nc+3
#pragma unroll
  for (int p = 0; p < 16; ++p) {
    int k = kr + p * 8;
    f32x4 v = *reinterpret_cast<const f32x4*>(&W[(size_t)(k0 + k) * N + n0 + nc]);
    int kx = k ^ phi_r;
#pragma unroll
    for (int i = 0; i < 4; ++i) t[nc + i][kx] = (bf16_t)v[i];
  }
  __syncthreads();
  // write phase: n-row = (tid>>4) + 16*pass, k-chunk = (tid&15)*8  (256B/row)
  const int nr = tid >> 4;
  const int kc = (tid & 15) * 8;
#pragma unroll
  for (int p = 0; p < 8; ++p) {
    int n = nr + p * 16;
    int ccx = kc ^ (8 * ((n >> 3) & 15));
    bf16x8 v = *reinterpret_cast<const bf16x8*>(&t[n][ccx]);
    *reinterpret_cast<bf16x8*>(&Wt[(size_t)(n0 + n) * K + k0 + kc]) = v;
  }
}

// all layers x all 4 weights in one dispatch (big-ws path), 128x128 tiles
// per layer: Wqkv 18x6=108, Wout 6x6=36, W1 24x6=144, W2 6x24=144 -> 432 tiles
__global__ __launch_bounds__(256) void transpose_all(const float* __restrict__ Wqkv,
                                                     const float* __restrict__ Wout,
                                                     const float* __restrict__ W1,
                                                     const float* __restrict__ W2,
                                                     bf16_t* __restrict__ wtall) {
  const int l = blockIdx.y;
  const int t = blockIdx.x;
  bf16_t* wl = wtall + (size_t)l * WT_LAYER;
  if (t < 108) {                                   // Wqkv: K=768, N=2304
    transpose_tile128(Wqkv + (size_t)l * DMODEL * QKVD, wl + WT_QKV,
                      DMODEL, QKVD, (t % 18) * 128, (t / 18) * 128);
  } else if (t < 144) {                            // Wout: 768x768
    int u = t - 108;
    transpose_tile128(Wout + (size_t)l * DMODEL * DMODEL, wl + WT_WOUT,
                      DMODEL, DMODEL, (u % 6) * 128, (u / 6) * 128);
  } else if (t < 288) {                            // W1: K=768, N=3072
    int u = t - 144;
    transpose_tile128(W1 + (size_t)l * DMODEL * DFFN, wl + WT_W1,
                      DMODEL, DFFN, (u % 24) * 128, (u / 24) * 128);
  } else {                                         // W2: K=3072, N=768
    int u = t - 288;
    transpose_tile128(W2 + (size_t)l * DFFN * DMODEL, wl + WT_W2,
                      DFFN, DMODEL, (u % 6) * 128, (u / 6) * 128);
  }
}

// ---------------- GEMM 128x128: C = A @ Bt^T, depth-2 pipeline + T2 LDS swizzle ------
template <int EPI>
__global__ __launch_bounds__(256) void gemm_bt(const bf16_t* __restrict__ A,
                                               const bf16_t* __restrict__ Bt,
                                               int M, int N, int K,
                                               const float* __restrict__ bias,
                                               bf16_t* __restrict__ Cb) {
  __shared__ alignas(16) bf16_t lA[3][128 * 32];
  __shared__ alignas(16) bf16_t lB[3][128 * 32];
  const int tid = threadIdx.x;
  const int lane = tid & 63;
  const int wid = tid >> 6;
  const int wr = wid >> 1, wc = wid & 1;
  int bx, by;
  swz_block(gridDim.x, gridDim.y, bx, by);
  const int brow = by * 128, bcol = bx * 128;

  f32x4 acc[4][4];
#pragma unroll
  for (int i = 0; i < 4; ++i)
#pragma unroll
    for (int j = 0; j < 4; ++j) acc[i][j] = zero4();

  const int arow = tid >> 2;
  const int acol = (((tid & 3) ^ ((tid >> 3) & 3))) * 8;   // inverse-swizzled source chunk
  const bf16_t* aptr = A + (size_t)(brow + arow) * K + acol;
  const bf16_t* bptr = Bt + (size_t)(bcol + arow) * K + acol;
  const int ldsoff = tid * 8;

  const int nk = K / 32;
  const int fro = (lane & 15) * 32 + (((lane >> 4) ^ (((lane & 15) >> 1) & 3))) * 8;

  auto STAGE = [&](int buf, int kt) {
    const bf16_t* a = aptr + kt * 32;
    const bf16_t* b = bptr + kt * 32;
    gload_lds16(a, &lA[buf][ldsoff]);
    gload_lds16(a + (size_t)64 * K, &lA[buf][ldsoff + 2048]);
    gload_lds16(b, &lB[buf][ldsoff]);
    gload_lds16(b + (size_t)64 * K, &lB[buf][ldsoff + 2048]);
  };

  auto BODY = [&](int kt) {
    const int cur = kt % 3;
    __builtin_amdgcn_s_barrier();
    bf16x8 af[4], bfr[4];
#pragma unroll
    for (int mi = 0; mi < 4; ++mi)
      af[mi] = *reinterpret_cast<const bf16x8*>(&lA[cur][(wr * 64 + mi * 16) * 32 + fro]);
#pragma unroll
    for (int ni = 0; ni < 4; ++ni)
      bfr[ni] = *reinterpret_cast<const bf16x8*>(&lB[cur][(wc * 64 + ni * 16) * 32 + fro]);
    if (kt + 2 < nk) STAGE((kt + 2) % 3, kt + 2);
#pragma unroll
    for (int mi = 0; mi < 4; ++mi)
#pragma unroll
      for (int ni = 0; ni < 4; ++ni)
        acc[mi][ni] = __builtin_amdgcn_mfma_f32_16x16x32_bf16(af[mi], bfr[ni], acc[mi][ni], 0, 0, 0);
  };

  STAGE(0, 0);
  STAGE(1, 1);
  for (int kt = 0; kt < nk; ++kt) {
    if (kt < nk - 1) asm volatile("s_waitcnt vmcnt(4)" ::: "memory");
    else             asm volatile("s_waitcnt vmcnt(0)" ::: "memory");
    BODY(kt);
  }

#pragma unroll
  for (int mi = 0; mi < 4; ++mi) {
    int rowb = brow + wr * 64 + mi * 16 + (lane >> 4) * 4;
#pragma unroll
    for (int ni = 0; ni < 4; ++ni) {
      int col = bcol + wc * 64 + ni * 16 + (lane & 15);
#pragma unroll
      for (int r = 0; r < 4; ++r) {
        float v = acc[mi][ni][r];
        size_t idx = (size_t)(rowb + r) * N + col;
        if (EPI == 0) {
          Cb[idx] = (bf16_t)v;
        } else {
          v += bias[col];
          v = 0.5f * v * (1.0f + erff(v * 0.70710678118f));
          Cb[idx] = (bf16_t)v;
        }
      }
    }
  }
}

// ---------------- GEMM 64x128 (N=768 shapes): depth-3 pipeline + T2 swizzle ---------
__global__ __launch_bounds__(256) void gemm_sm(const bf16_t* __restrict__ A,
                                               const bf16_t* __restrict__ Bt,
                                               int M, int N, int K,
                                               const float* __restrict__ bias,
                                               float* __restrict__ hres) {
  __shared__ alignas(16) bf16_t lA[4][64 * 32];
  __shared__ alignas(16) bf16_t lB[4][128 * 32];
  const int tid = threadIdx.x;
  const int lane = tid & 63;
  const int wid = tid >> 6;
  int bx, by;
  swz_block(gridDim.x, gridDim.y, bx, by);
  const int brow = by * 64, bcol = bx * 128;

  f32x4 acc[4][2];
#pragma unroll
  for (int i = 0; i < 4; ++i)
#pragma unroll
    for (int j = 0; j < 2; ++j) acc[i][j] = zero4();

  const int arow = tid >> 2;
  const int acol = (((tid & 3) ^ ((tid >> 3) & 3))) * 8;
  const bf16_t* aptr = A + (size_t)(brow + arow) * K + acol;
  const bf16_t* bptr = Bt + (size_t)(bcol + arow) * K + acol;
  const int ldsoff = tid * 8;

  const int nk = K / 32;
  const int fro = (lane & 15) * 32 + (((lane >> 4) ^ (((lane & 15) >> 1) & 3))) * 8;

  auto STAGE = [&](int buf, int kt) {
    const bf16_t* a = aptr + kt * 32;
    const bf16_t* b = bptr + kt * 32;
    gload_lds16(a, &lA[buf][ldsoff]);
    gload_lds16(b, &lB[buf][ldsoff]);
    gload_lds16(b + (size_t)64 * K, &lB[buf][ldsoff + 2048]);
  };

  auto BODY = [&](int kt) {
    const int cur = kt & 3;
    __builtin_amdgcn_s_barrier();
    bf16x8 af[4], bfr[2];
#pragma unroll
    for (int mi = 0; mi < 4; ++mi)
      af[mi] = *reinterpret_cast<const bf16x8*>(&lA[cur][mi * 512 + fro]);
#pragma unroll
    for (int ni = 0; ni < 2; ++ni)
      bfr[ni] = *reinterpret_cast<const bf16x8*>(&lB[cur][(wid * 32 + ni * 16) * 32 + fro]);
    if (kt + 3 < nk) STAGE((kt + 3) & 3, kt + 3);
#pragma unroll
    for (int mi = 0; mi < 4; ++mi)
#pragma unroll
      for (int ni = 0; ni < 2; ++ni)
        acc[mi][ni] = __builtin_amdgcn_mfma_f32_16x16x32_bf16(af[mi], bfr[ni], acc[mi][ni], 0, 0, 0);
  };

  STAGE(0, 0);
  STAGE(1, 1);
  STAGE(2, 2);
  for (int kt = 0; kt < nk; ++kt) {
    if (kt < nk - 2)       asm volatile("s_waitcnt vmcnt(6)" ::: "memory");
    else if (kt == nk - 2) asm volatile("s_waitcnt vmcnt(3)" ::: "memory");
    else                   asm volatile("s_waitcnt vmcnt(0)" ::: "memory");
    BODY(kt);
  }

#pragma unroll
  for (int mi = 0; mi < 4; ++mi) {
    int rowb = brow + mi * 16 + (lane >> 4) * 4;
#pragma unroll
    for (int ni = 0; ni < 2; ++ni) {
      int col = bcol + wid * 32 + ni * 16 + (lane & 15);
#pragma unroll
      for (int r = 0; r < 4; ++r) {
        float v = acc[mi][ni][r] + bias[col];
        hres[(size_t)(rowb + r) * N + col] += v;
      }
    }
  }
}

// ---------------- Attention (flash-style), one block = (bh, 64 q rows) ----------------
__global__ __launch_bounds__(256) void attn_kernel(const bf16_t* __restrict__ qkv,
                                                   bf16_t* __restrict__ o) {
  const int qb = blockIdx.x;   // 0..15
  const int bh = blockIdx.y;   // 0..47
  const int b = bh / NHEADS, hh = bh % NHEADS;
  const int tid = threadIdx.x;
  const int lane = tid & 63, wid = tid >> 6;

  __shared__ alignas(16) bf16_t lK[2][64][72];
  __shared__ alignas(16) bf16_t lV[2][64][72];   // [d][j ^ 8*((d>>3)&7)]
  __shared__ alignas(16) bf16_t lP[4][16][72];   // wave-private P tiles

  bf16x8 qf[2];
  {
    int q = qb * 64 + wid * 16 + (lane & 15);
    const bf16_t* qrow = qkv + (size_t)(b * NSEQ + q) * QKVD + hh * HD + (lane >> 4) * 8;
    qf[0] = *reinterpret_cast<const bf16x8*>(qrow);
    qf[1] = *reinterpret_cast<const bf16x8*>(qrow + 32);
  }

  const int r = tid / 8;
  const int c = (tid % 8) * 8;
  const int vswz = (c & 0x38);
  const bf16_t* kbase = qkv + (size_t)(b * NSEQ) * QKVD + DMODEL + hh * HD + c;
  const bf16_t* vbase = qkv + (size_t)(b * NSEQ) * QKVD + 2 * DMODEL + hh * HD + c;

  bf16x8 kreg[2], vreg[2];
  auto LOADKV = [&](int j0) {
#pragma unroll
    for (int it = 0; it < 2; ++it) {
      int rr = r + it * 32;
      kreg[it] = *reinterpret_cast<const bf16x8*>(kbase + (size_t)(j0 + rr) * QKVD);
      vreg[it] = *reinterpret_cast<const bf16x8*>(vbase + (size_t)(j0 + rr) * QKVD);
    }
  };
  auto WRITEKV = [&](int buf) {
#pragma unroll
    for (int it = 0; it < 2; ++it) {
      int rr = r + it * 32;
      *reinterpret_cast<bf16x8*>(&lK[buf][rr][c]) = kreg[it];
      int col = rr ^ vswz;
#pragma unroll
      for (int i = 0; i < 8; ++i) lV[buf][c + i][col] = vreg[it][i];
    }
  };

  float m[4], lsum[4];
  f32x4 oacc[4];
#pragma unroll
  for (int rr = 0; rr < 4; ++rr) { m[rr] = -1e30f; lsum[rr] = 0.f; }
#pragma unroll
  for (int df = 0; df < 4; ++df) oacc[df] = zero4();

  LOADKV(0);
  WRITEKV(0);
  __syncthreads();

  for (int jb = 0; jb < 16; ++jb) {
    const int cur = jb & 1;
    if (jb < 15) LOADKV((jb + 1) * 64);

    f32x4 s[4];
    __builtin_amdgcn_s_setprio(1);
#pragma unroll
    for (int jf = 0; jf < 4; ++jf) {
      s[jf] = zero4();
#pragma unroll
      for (int dk = 0; dk < 2; ++dk) {
        bf16x8 kf = *reinterpret_cast<const bf16x8*>(
            &lK[cur][jf * 16 + (lane & 15)][(lane >> 4) * 8 + dk * 32]);
        s[jf] = __builtin_amdgcn_mfma_f32_16x16x32_bf16(qf[dk], kf, s[jf], 0, 0, 0);
      }
    }
    __builtin_amdgcn_s_setprio(0);

    float mx[4];
#pragma unroll
    for (int rr = 0; rr < 4; ++rr) {
      float v = -1e30f;
#pragma unroll
      for (int jf = 0; jf < 4; ++jf) {
        s[jf][rr] = s[jf][rr] * 0.125f;
        v = fmaxf(v, s[jf][rr]);
      }
#pragma unroll
      for (int msk = 1; msk < 16; msk <<= 1) v = fmaxf(v, __shfl_xor(v, msk));
      mx[rr] = v;
    }
    bool upd = (mx[0] > m[0] + 8.f) | (mx[1] > m[1] + 8.f) |
               (mx[2] > m[2] + 8.f) | (mx[3] > m[3] + 8.f);
    if (__any(upd)) {
      float fac[4];
#pragma unroll
      for (int rr = 0; rr < 4; ++rr) {
        float pm = fmaxf(m[rr], mx[rr]);
        fac[rr] = __expf(m[rr] - pm);
        m[rr] = pm;
        lsum[rr] *= fac[rr];
      }
#pragma unroll
      for (int df = 0; df < 4; ++df)
#pragma unroll
        for (int rr = 0; rr < 4; ++rr) oacc[df][rr] = oacc[df][rr] * fac[rr];
    }

    float rs[4] = {0.f, 0.f, 0.f, 0.f};
#pragma unroll
    for (int jf = 0; jf < 4; ++jf) {
#pragma unroll
      for (int rr = 0; rr < 4; ++rr) {
        float pv = __expf(s[jf][rr] - m[rr]);
        rs[rr] += pv;
        lP[wid][(lane >> 4) * 4 + rr][jf * 16 + (lane & 15)] = (bf16_t)pv;
      }
    }
#pragma unroll
    for (int rr = 0; rr < 4; ++rr) {
      float t = rs[rr];
#pragma unroll
      for (int msk = 1; msk < 16; msk <<= 1) t += __shfl_xor(t, msk);
      lsum[rr] += t;
    }

    __syncthreads();

    if (jb < 15) WRITEKV(cur ^ 1);

    __builtin_amdgcn_s_setprio(1);
#pragma unroll
    for (int df = 0; df < 4; ++df) {
      int d = df * 16 + (lane & 15);
      int rsw = (d & 0x38);
#pragma unroll
      for (int js = 0; js < 2; ++js) {
        bf16x8 pf = *reinterpret_cast<const bf16x8*>(
            &lP[wid][lane & 15][(lane >> 4) * 8 + js * 32]);
        bf16x8 vf = *reinterpret_cast<const bf16x8*>(
            &lV[cur][d][((lane >> 4) * 8 + js * 32) ^ rsw]);
        oacc[df] = __builtin_amdgcn_mfma_f32_16x16x32_bf16(pf, vf, oacc[df], 0, 0, 0);
      }
    }
    __builtin_amdgcn_s_setprio(0);

    __syncthreads();
  }

  int q0 = qb * 64 + wid * 16 + (lane >> 4) * 4;
#pragma unroll
  for (int rr = 0; rr < 4; ++rr) {
    float inv = 1.0f / lsum[rr];
#pragma unroll
    for (int df = 0; df < 4; ++df) {
      int col = hh * HD + df * 16 + (lane & 15);
      o[(size_t)(b * NSEQ + q0 + rr) * DMODEL + col] = (bf16_t)(oacc[df][rr] * inv);
    }
  }
}

// ---------------- host launch ----------------
extern "C" void kernel_launch(void* const* d_in, const int* in_sizes, int n_in,
                              void* d_out, int out_size, void* d_ws, size_t ws_size,
                              hipStream_t stream) {
  const float* x    = (const float*)d_in[0];
  const float* Wqkv = (const float*)d_in[1];
  const float* Wout = (const float*)d_in[2];
  const float* bout = (const float*)d_in[3];
  const float* ln1g = (const float*)d_in[4];
  const float* ln1b = (const float*)d_in[5];
  const float* W1   = (const float*)d_in[6];
  const float* b1   = (const float*)d_in[7];
  const float* W2   = (const float*)d_in[8];
  const float* b2   = (const float*)d_in[9];
  const float* ln2g = (const float*)d_in[10];
  const float* ln2b = (const float*)d_in[11];
  const float* lnfg = (const float*)d_in[12];
  const float* lnfb = (const float*)d_in[13];

  char* p = (char*)d_ws;
  float*  h   = (float*)p;
  bf16_t* xn  = (bf16_t*)(p + 12582912);
  bf16_t* big = (bf16_t*)(p + 18874368);
  bf16_t* wt  = (bf16_t*)(p + 44040192);
  bf16_t* attno = xn;
  bf16_t* qkvb  = big;
  bf16_t* ffh   = big;

  const bool bigws = ws_size >= 157286400ull;

  init_h_kernel<<<TOK * DMODEL / 1024, 256, 0, stream>>>(x, h);
  if (bigws)
    transpose_all<<<dim3(432, NLAYER), 256, 0, stream>>>(Wqkv, Wout, W1, W2, wt);

  for (int l = 0; l < NLAYER; ++l) {
    const bf16_t* wl = wt + (size_t)l * WT_LAYER;
    const bf16_t* qkv_t  = bigws ? wl + WT_QKV  : wt;
    const bf16_t* wout_t = bigws ? wl + WT_WOUT : wt;
    const bf16_t* w1_t   = bigws ? wl + WT_W1   : wt;
    const bf16_t* w2_t   = bigws ? wl + WT_W2   : wt;

    // 1) LN1 -> xn ; QKV GEMM -> qkvb
    if (!bigws)
      transpose_w<<<dim3(QKVD / 64, DMODEL / 64), 256, 0, stream>>>(
          Wqkv + (size_t)l * DMODEL * QKVD, wt, DMODEL, QKVD);
    ln_kernel<bf16_t><<<TOK, 256, 0, stream>>>(h, ln1g + l * DMODEL, ln1b + l * DMODEL, xn);
    gemm_bt<0><<<dim3(QKVD / 128, TOK / 128), 256, 0, stream>>>(
        xn, qkv_t, TOK, QKVD, DMODEL, nullptr, qkvb);

    // 2) attention -> attno (aliases xn, xn is dead)
    attn_kernel<<<dim3(16, 48), 256, 0, stream>>>(qkvb, attno);

    // 3) out-proj, h += attno @ Wout + bout  (64x128 tiles, 384 blocks)
    if (!bigws)
      transpose_w<<<dim3(DMODEL / 64, DMODEL / 64), 256, 0, stream>>>(
          Wout + (size_t)l * DMODEL * DMODEL, wt, DMODEL, DMODEL);
    gemm_sm<<<dim3(DMODEL / 128, TOK / 64), 256, 0, stream>>>(
        attno, wout_t, TOK, DMODEL, DMODEL, bout + l * DMODEL, h);

    // 4) LN2 -> xn ; FF1 (gelu) -> ffh
    if (!bigws)
      transpose_w<<<dim3(DFFN / 64, DMODEL / 64), 256, 0, stream>>>(
          W1 + (size_t)l * DMODEL * DFFN, wt, DMODEL, DFFN);
    ln_kernel<bf16_t><<<TOK, 256, 0, stream>>>(h, ln2g + l * DMODEL, ln2b + l * DMODEL, xn);
    gemm_bt<1><<<dim3(DFFN / 128, TOK / 128), 256, 0, stream>>>(
        xn, w1_t, TOK, DFFN, DMODEL, b1 + l * DFFN, ffh);

    // 5) FF2, h += ffh @ W2 + b2  (64x128 tiles, 384 blocks)
    if (!bigws)
      transpose_w<<<dim3(DMODEL / 64, DFFN / 64), 256, 0, stream>>>(
          W2 + (size_t)l * DFFN * DMODEL, wt, DFFN, DMODEL);
    gemm_sm<<<dim3(DMODEL / 128, TOK / 64), 256, 0, stream>>>(
        ffh, w2_t, TOK, DMODEL, DFFN, b2 + l * DMODEL, h);
  }

  ln_kernel<float><<<TOK, 256, 0, stream>>>(h, lnfg, lnfb, (float*)d_out);
}